// Round 7
// baseline (186.334 us; speedup 1.0000x reference)
//
#include <hip/hip_runtime.h>

// MSD via MFMA. R14: pre-pack origin (B) rows to bf16 in MFMA-fragment order;
// feed MFMA B-operand directly from global/L2. Kills the B LDS tile and the
// 111x-redundant per-block f32->bf16 B conversion.
// msd[td] = (1/(180*1536)) * sum_i ( S[t] + S[100i] - 2*<x[t],x[100i]> ), t=100i+td
//
// R13 post-mortem: 181.5 = 141 harness fills + dot 31 + reduce ~7.5. Dot's
// VALU (staging conversions, ~330 instr/thread, ~21 us/CU) ~= its HBM time
// (~20 us) with imperfect overlap at 6 blocks/CU. B-side staging is pure
// redundancy: 5000 blocks x 6144 packs for 276K unique elements.
// Fix: msd_packb writes xbF[kc][ks][i][32] (bf16 fragment layout: lane(m,quad)
// reads 8 contiguous bf16 at ((kc*6+ks)*180+i)*32 + quad*8). A wave's B-frag
// load = 16 consecutive origins x 64B = 1 contiguous 1KB span, L2-resident
// (138 KB/plane, XCD-local via bid%8==kc). LDS drops to 12.8 KB (lA only) ->
// 8 blocks/CU (thread-slot capped) = 32 waves/CU.
// A staging + inline S unchanged (f32 sumsq before bf16 pack).
// ws: 8 dot planes (11.52 MB) + 8 S planes (640 KB) + part (64 KB)
//     + xbF (540 KB) = 12.8 MB.
// bf16 cross term only (absmax 7.8e-3 << 4e-2, stable R6-R13).

typedef __attribute__((ext_vector_type(8))) short bf16x8;
typedef __attribute__((ext_vector_type(4))) short bf16x4;
typedef __attribute__((ext_vector_type(4))) float f32x4;

#define ROWF   1536
#define NFRAME 20000
#define NORIG  180
#define WIN    20
#define FB     32
#define NFB    625      // 625*32 = 20000 exactly
#define NKC    8        // K planes
#define KC     192      // 1536 / 8
#define NKS    6        // 192 / 32
#define TDMAX  2000
#define PLANE  (NORIG * TDMAX)          // 360000 floats per K-plane
#define SOFF   (NKC * PLANE)            // S planes after dot planes
#define POFF   (SOFF + NKC * NFRAME)    // stage-1 partials after S planes
#define XBOFF  (POFF + 8 * TDMAX)       // bf16 fragment buffer (as shorts)
#define LROW   200                      // 192 bf16 + 8 pad -> 400B row stride
#define SCALE  (1.0f / (1536.0f * 180.0f))

static __device__ __forceinline__ short f2bf(float f) {
    unsigned u = __builtin_bit_cast(unsigned, f);
    u += 0x7fffu + ((u >> 16) & 1u);
    return (short)(u >> 16);
}

static __device__ __forceinline__ bf16x4 pack4(const float4& v) {
    bf16x4 r;
    r[0] = f2bf(v.x); r[1] = f2bf(v.y); r[2] = f2bf(v.z); r[3] = f2bf(v.w);
    return r;
}

// Pack the 180 origin rows to bf16 in MFMA-fragment order:
// element k = kc*192 + ks*32 + quad*8 + e of origin i lands at
// xb[((kc*6+ks)*180 + i)*32 + quad*8 + e].
__global__ __launch_bounds__(256)
void msd_packb_kernel(const float* __restrict__ x, short* __restrict__ xb) {
    const int i = blockIdx.x;                 // 0..179 (frame 100*i)
    #pragma unroll
    for (int it = 0; it < 2; ++it) {
        const int idx = it * 256 + threadIdx.x;   // float4 index within row
        if (idx < 384) {
            const float4 v = *(const float4*)(x + (size_t)(i * 100) * ROWF + idx * 4);
            const int kc   = idx / 48;            // 48 float4 per K-plane
            const int ks   = (idx % 48) >> 3;     // 8 float4 per ks
            const int quad = (idx & 7) >> 1;
            const int e    = (idx & 1) * 4;
            xb[(((size_t)(kc * NKS + ks)) * NORIG + i) * 32 + quad * 8 + e + 0] = f2bf(v.x);
            xb[(((size_t)(kc * NKS + ks)) * NORIG + i) * 32 + quad * 8 + e + 1] = f2bf(v.y);
            xb[(((size_t)(kc * NKS + ks)) * NORIG + i) * 32 + quad * 8 + e + 2] = f2bf(v.z);
            xb[(((size_t)(kc * NKS + ks)) * NORIG + i) * 32 + quad * 8 + e + 3] = f2bf(v.w);
        }
    }
}

__global__ __launch_bounds__(256)
void msd_dot_kernel(const float* __restrict__ x, const short* __restrict__ xb,
                    float* __restrict__ ws) {
    __shared__ short lA[FB * LROW];   // 12800 B (A tile only)

    const int fb  = blockIdx.x >> 3;    // frame block
    const int kc  = blockIdx.x & 7;     // K plane
    const int t0  = fb * FB;
    const int tid = threadIdx.x;

    const int cmin = t0 / 100;
    int iBase = cmin - (WIN - 1); if (iBase < 0) iBase = 0;

    // ---- stage A (row-grouped) + inline f32 sumsq ----
    {
        const int r  = tid >> 3;
        const int c8 = tid & 7;
        const float* src = x + (size_t)(t0 + r) * ROWF + kc * KC + c8 * 4;
        short* dst = &lA[r * LROW + c8 * 4];
        float sq = 0.0f;
        #pragma unroll
        for (int it = 0; it < 6; ++it) {
            const float4 v = *(const float4*)(src + it * 32);
            sq += v.x*v.x + v.y*v.y + v.z*v.z + v.w*v.w;
            *(bf16x4*)(dst + it * 32) = pack4(v);
        }
        sq += __shfl_xor(sq, 1, 64);
        sq += __shfl_xor(sq, 2, 64);
        sq += __shfl_xor(sq, 4, 64);
        if (c8 == 0)
            ws[SOFF + (size_t)kc * NFRAME + t0 + r] = sq;   // plane-partial S
    }
    __syncthreads();

    // ---- MFMA: A from LDS, B fragments straight from global (L2) ----
    const int lane = tid & 63;
    const int w    = tid >> 6;   // 4 waves
    const int mt   = w >> 1;     // frame half (16 frames)
    const int nt   = w & 1;      // origin half (16 slots)
    const int m    = lane & 15;
    const int quad = lane >> 4;

    const int iNom = iBase + 16 * nt + m;              // B origin, nominal
    const int iClp = (iNom < NORIG) ? iNom : (NORIG - 1);

    const short* pa  = &lA[(16 * mt + m) * LROW + quad * 8];
    const short* pbg = xb + ((size_t)(kc * NKS) * NORIG + iClp) * 32 + quad * 8;

    f32x4 acc = {};
    #pragma unroll
    for (int ks = 0; ks < NKS; ++ks) {
        acc = __builtin_amdgcn_mfma_f32_16x16x32_bf16(
            *(const bf16x8*)(pa + ks * 32),
            *(const bf16x8*)(pbg + (size_t)ks * NORIG * 32),
            acc, 0, 0, 0);
    }

    // C/D layout: col = lane&15 (origin slot), row = quad*4 + r (frame-in-tile).
    float* wsp = ws + (size_t)kc * PLANE;
    #pragma unroll
    for (int r = 0; r < 4; ++r) {
        const int j  = 16 * mt + quad * 4 + r;     // frame within block
        const int tt = t0 + j;
        const int c  = tt / 100;
        const int i  = iBase + 16 * nt + m;        // nominal origin of this col
        const int k  = c - i;
        if (k >= 0 && k < WIN && i < NORIG) {
            const int td = tt - 100 * i;           // in [0, 2000)
            wsp[(size_t)i * TDMAX + td] = acc[r];
        }
    }
}

// Stage 1: 256 blocks = (32 td-chunks) x (8 i-chunks). Lanes = consecutive td.
__global__ __launch_bounds__(256)
void msd_reduce1_kernel(const float* __restrict__ ws, float* __restrict__ part) {
    __shared__ float red[4][64];
    const int bx      = blockIdx.x;
    const int tdChunk = bx >> 3;
    const int iChunk  = bx & 7;
    const int lane = threadIdx.x & 63;
    const int w    = threadIdx.x >> 6;
    const int td   = tdChunk * 64 + lane;
    const int tdc  = (td < TDMAX) ? td : (TDMAX - 1);   // clamp, no OOB
    const float* Sp = ws + SOFF;

    const int i0 = iChunk * 23;
    const int i1 = (i0 + 23 < NORIG) ? (i0 + 23) : NORIG;

    float acc = 0.0f;
    for (int i = i0 + w; i < i1; i += 4) {       // ~6 iters per thread
        const int t = 100 * i + tdc;
        float St = 0.0f, Si = 0.0f, D = 0.0f;
        #pragma unroll
        for (int kcp = 0; kcp < NKC; ++kcp) {
            St += Sp[(size_t)kcp * NFRAME + t];            // coalesced
            Si += Sp[(size_t)kcp * NFRAME + 100 * i];      // broadcast
            D  += ws[(size_t)kcp * PLANE + (size_t)i * TDMAX + tdc];  // coalesced
        }
        acc += St + Si - 2.0f * D;
    }
    red[w][lane] = acc;
    __syncthreads();
    if (w == 0 && td < TDMAX)
        part[(size_t)iChunk * TDMAX + td] =
            red[0][lane] + red[1][lane] + red[2][lane] + red[3][lane];
}

// Stage 2: out[td] = SCALE * sum_j part[j][td]. 8 blocks x 256, coalesced.
__global__ __launch_bounds__(256)
void msd_reduce2_kernel(const float* __restrict__ part, float* __restrict__ out) {
    const int td = blockIdx.x * 256 + threadIdx.x;
    if (td >= TDMAX) return;
    float a = 0.0f;
    #pragma unroll
    for (int j = 0; j < 8; ++j)
        a += part[(size_t)j * TDMAX + td];
    out[td] = a * SCALE;
}

extern "C" void kernel_launch(void* const* d_in, const int* in_sizes, int n_in,
                              void* d_out, int out_size, void* d_ws, size_t ws_size,
                              hipStream_t stream) {
    const float* x = (const float*)d_in[0];
    float* out = (float*)d_out;
    float* ws  = (float*)d_ws;    // needs (XBOFF + 180*1536/2)*4 ~= 12.8 MB
    short* xb  = (short*)(ws + XBOFF);

    msd_packb_kernel<<<NORIG, 256, 0, stream>>>(x, xb);
    msd_dot_kernel<<<NFB * NKC, 256, 0, stream>>>(x, xb, ws);
    msd_reduce1_kernel<<<256, 256, 0, stream>>>(ws, ws + POFF);
    msd_reduce2_kernel<<<8, 256, 0, stream>>>(ws + POFF, out);
}

// Round 8
// 184.240 us; speedup vs baseline: 1.0114x; 1.0114x over previous
//
#include <hip/hip_runtime.h>

// MSD via MFMA. R15: exact R13 structure (proven: 181.5 us total, dot 31 us),
// with f32->bf16 packing done by v_cvt_pk_bf16_f32 (1 VALU op / 2 elems)
// instead of the 4-op/elem bit-twiddle.
// msd[td] = (1/(180*1536)) * sum_i ( S[t] + S[100i] - 2*<x[t],x[100i]> ), t=100i+td
//
// R14 post-mortem: feeding MFMA's B operand from global/L2 regressed (+5 us)
// -- per-K-step vmcnt stalls beat the saved VALU; packb launch added cost.
// Reverted. R13 residual analysis: dot = 31 us vs ~20 us HBM floor; staging
// pack VALU ~ 190 instr/thread ~ 23 us/CU, co-dominant with HBM and not fully
// overlapped at 6 blocks/CU. Fix in place: cvt_pk halves nothing structural,
// just cuts pack VALU ~8x (48 elems: ~190 ops -> 24 ops). RTNE == old twiddle,
// numerics unchanged (absmax 7.8e-3 << 4e-2, stable R6-R14).
// ws: 8 dot planes [kc][i][td] (11.52 MB) + 8 S planes [kc][t] (640 KB)
//     + part [8][2000] (64 KB) = 12.23 MB.

typedef __attribute__((ext_vector_type(8))) short bf16x8;
typedef __attribute__((ext_vector_type(4))) float f32x4;

#define ROWF   1536
#define NFRAME 20000
#define NORIG  180
#define WIN    20
#define FB     32
#define NFB    625      // 625*32 = 20000 exactly
#define NKC    8        // K planes
#define KC     192      // 1536 / 8
#define NKS    6        // 192 / 32
#define TDMAX  2000
#define PLANE  (NORIG * TDMAX)          // 360000 floats per K-plane
#define SOFF   (NKC * PLANE)            // S planes after dot planes
#define POFF   (SOFF + NKC * NFRAME)    // stage-1 partials after S planes
#define LROW   200                      // 192 bf16 + 8 pad -> 400B row stride
#define SCALE  (1.0f / (1536.0f * 180.0f))

// f32 pair -> packed bf16x2 (RTNE), single VALU op. No gfx950 builtin; pure
// register dataflow so no sched_barrier needed (guide T12 recipe).
static __device__ __forceinline__ unsigned cvtpk(float lo, float hi) {
    unsigned r;
    asm("v_cvt_pk_bf16_f32 %0, %1, %2" : "=v"(r) : "v"(lo), "v"(hi));
    return r;
}

__global__ __launch_bounds__(256)
void msd_dot_kernel(const float* __restrict__ x, float* __restrict__ ws) {
    __shared__ short lA[FB * LROW];   // 12800 B
    __shared__ short lB[FB * LROW];   // 12800 B

    const int fb  = blockIdx.x >> 3;    // frame block
    const int kc  = blockIdx.x & 7;     // K plane
    const int t0  = fb * FB;
    const int tid = threadIdx.x;

    const int cmin = t0 / 100;
    int iBase = cmin - (WIN - 1); if (iBase < 0) iBase = 0;

    // ---- stage A (row-grouped) + inline f32 sumsq ----
    // 32 rows x 48 float4; thread (r = tid>>3, c8 = tid&7) loads 6 float4s
    // of row r at columns c8 + 8*it. Wave = 8 rows x 128B contiguous segments.
    {
        const int r  = tid >> 3;
        const int c8 = tid & 7;
        const float* src = x + (size_t)(t0 + r) * ROWF + kc * KC + c8 * 4;
        short* dst = &lA[r * LROW + c8 * 4];
        float sq = 0.0f;
        #pragma unroll
        for (int it = 0; it < 6; ++it) {
            const float4 v = *(const float4*)(src + it * 32);
            sq += v.x*v.x + v.y*v.y + v.z*v.z + v.w*v.w;
            uint2 p; p.x = cvtpk(v.x, v.y); p.y = cvtpk(v.z, v.w);
            *(uint2*)(dst + it * 32) = p;
        }
        sq += __shfl_xor(sq, 1, 64);
        sq += __shfl_xor(sq, 2, 64);
        sq += __shfl_xor(sq, 4, 64);
        if (c8 == 0)
            ws[SOFF + (size_t)kc * NFRAME + t0 + r] = sq;   // plane-partial S
    }
    // ---- stage B: 32 origin rows (clamped), same mapping, no S needed ----
    {
        const int r  = tid >> 3;
        const int c8 = tid & 7;
        const int iNom = iBase + r;
        const int iClp = (iNom < NORIG) ? iNom : (NORIG - 1);
        const float* src = x + (size_t)(iClp * 100) * ROWF + kc * KC + c8 * 4;
        short* dst = &lB[r * LROW + c8 * 4];
        #pragma unroll
        for (int it = 0; it < 6; ++it) {
            const float4 v = *(const float4*)(src + it * 32);
            uint2 p; p.x = cvtpk(v.x, v.y); p.y = cvtpk(v.z, v.w);
            *(uint2*)(dst + it * 32) = p;
        }
    }
    __syncthreads();

    // ---- MFMA from LDS ----
    const int lane = tid & 63;
    const int w    = tid >> 6;   // 4 waves
    const int mt   = w >> 1;     // frame half (16 frames)
    const int nt   = w & 1;      // origin half (16 slots)
    const int m    = lane & 15;
    const int quad = lane >> 4;

    const short* pa = &lA[(16 * mt + m) * LROW + quad * 8];
    const short* pb = &lB[(16 * nt + m) * LROW + quad * 8];

    f32x4 acc = {};
    #pragma unroll
    for (int ks = 0; ks < NKS; ++ks) {
        acc = __builtin_amdgcn_mfma_f32_16x16x32_bf16(*(const bf16x8*)(pa + ks * 32),
                                                      *(const bf16x8*)(pb + ks * 32),
                                                      acc, 0, 0, 0);
    }

    // C/D layout: col = lane&15 (origin slot), row = quad*4 + r (frame-in-tile).
    // Store raw dot plane-partial into [kc][i][td]; each valid (i,td) is
    // produced by exactly one frame-block (t = 100i+td), no collisions.
    float* wsp = ws + (size_t)kc * PLANE;
    #pragma unroll
    for (int r = 0; r < 4; ++r) {
        const int j  = 16 * mt + quad * 4 + r;     // frame within block
        const int tt = t0 + j;
        const int c  = tt / 100;
        const int i  = iBase + 16 * nt + m;        // nominal origin of this col
        const int k  = c - i;
        if (k >= 0 && k < WIN && i < NORIG) {
            const int td = tt - 100 * i;           // in [0, 2000)
            wsp[(size_t)i * TDMAX + td] = acc[r];
        }
    }
}

// Stage 1: 256 blocks = (32 td-chunks) x (8 i-chunks). Lanes = consecutive td.
// part[iChunk][td] = sum over the chunk's origins of (S[t]+S[100i]-2*dot).
__global__ __launch_bounds__(256)
void msd_reduce1_kernel(const float* __restrict__ ws, float* __restrict__ part) {
    __shared__ float red[4][64];
    const int bx      = blockIdx.x;
    const int tdChunk = bx >> 3;
    const int iChunk  = bx & 7;
    const int lane = threadIdx.x & 63;
    const int w    = threadIdx.x >> 6;
    const int td   = tdChunk * 64 + lane;
    const int tdc  = (td < TDMAX) ? td : (TDMAX - 1);   // clamp, no OOB
    const float* Sp = ws + SOFF;

    const int i0 = iChunk * 23;
    const int i1 = (i0 + 23 < NORIG) ? (i0 + 23) : NORIG;

    float acc = 0.0f;
    for (int i = i0 + w; i < i1; i += 4) {       // ~6 iters per thread
        const int t = 100 * i + tdc;
        float St = 0.0f, Si = 0.0f, D = 0.0f;
        #pragma unroll
        for (int kcp = 0; kcp < NKC; ++kcp) {
            St += Sp[(size_t)kcp * NFRAME + t];            // coalesced
            Si += Sp[(size_t)kcp * NFRAME + 100 * i];      // broadcast
            D  += ws[(size_t)kcp * PLANE + (size_t)i * TDMAX + tdc];  // coalesced
        }
        acc += St + Si - 2.0f * D;
    }
    red[w][lane] = acc;
    __syncthreads();
    if (w == 0 && td < TDMAX)
        part[(size_t)iChunk * TDMAX + td] =
            red[0][lane] + red[1][lane] + red[2][lane] + red[3][lane];
}

// Stage 2: out[td] = SCALE * sum_j part[j][td]. 8 blocks x 256, coalesced.
__global__ __launch_bounds__(256)
void msd_reduce2_kernel(const float* __restrict__ part, float* __restrict__ out) {
    const int td = blockIdx.x * 256 + threadIdx.x;
    if (td >= TDMAX) return;
    float a = 0.0f;
    #pragma unroll
    for (int j = 0; j < 8; ++j)
        a += part[(size_t)j * TDMAX + td];
    out[td] = a * SCALE;
}

extern "C" void kernel_launch(void* const* d_in, const int* in_sizes, int n_in,
                              void* d_out, int out_size, void* d_ws, size_t ws_size,
                              hipStream_t stream) {
    const float* x = (const float*)d_in[0];
    float* out = (float*)d_out;
    float* ws  = (float*)d_ws;    // needs (POFF + 8*2000)*4 = 12.23 MB

    msd_dot_kernel<<<NFB * NKC, 256, 0, stream>>>(x, ws);
    msd_reduce1_kernel<<<256, 256, 0, stream>>>(ws, ws + POFF);
    msd_reduce2_kernel<<<8, 256, 0, stream>>>(ws + POFF, out);
}